// Round 1
// 491.479 us; speedup vs baseline: 1.0016x; 1.0016x over previous
//
#include <hip/hip_runtime.h>
#include <math.h>

// Problem shape (from reference setup_inputs): B=65536 rows, C=1000 cols, fp32.
#define C_DIM 1000
#define NV4   (C_DIM / 4)      // 250 float4 per row
#define WPB   4                // waves per block -> 4 rows per block
#define PAD_O (-100.0f)        // exp(PAD_O) == 0; with t=0 contributes nothing

__device__ __forceinline__ float wave_sum(float v) {
#pragma unroll
    for (int off = 32; off > 0; off >>= 1)
        v += __shfl_xor(v, off, 64);
    return v;
}

// Five interleaved butterfly chains — DS latency overlapped 5-wide.
__device__ __forceinline__ void wave_sum5(float v[5]) {
#pragma unroll
    for (int off = 32; off > 0; off >>= 1) {
        float x[5];
#pragma unroll
        for (int i = 0; i < 5; ++i) x[i] = __shfl_xor(v[i], off, 64);
#pragma unroll
        for (int i = 0; i < 5; ++i) v[i] += x[i];
    }
}

// One wave = one row. Algebraic refactor keeps only TWO masked values per
// element (em = pos?e:0, tp = pos?t:0) live across the wave reduction:
//   sum_p loss_p = T*Lsum + Ltw - P*Aneg - Apos
//   Lsum = sum_p log(S+e_p), Ltw = sum_p t_p*log(S+e_p)
// where Aneg, Apos, T, S, P all come out of pass 1. Live state ~32 floats
// (vs 96 before) -> no AGPR spill churn, higher occupancy.
__global__ __launch_bounds__(256, 6) void mvce_rows(
    const float* __restrict__ outp, const float* __restrict__ tgtp,
    float* __restrict__ partial)
{
    const int lane = threadIdx.x & 63;
    const int wave = threadIdx.x >> 6;
    const int row  = blockIdx.x * WPB + wave;

    const float4* __restrict__ o4 = reinterpret_cast<const float4*>(outp + (size_t)row * C_DIM);
    const float4* __restrict__ t4 = reinterpret_cast<const float4*>(tgtp + (size_t)row * C_DIM);

    // ---- Load phase: 4 o + 4 t float4 per lane, all issued before compute ----
    float4 ov[4], tv[4];
#pragma unroll
    for (int it = 0; it < 4; ++it) {
        const int j = lane + 64 * it;
        if (j < NV4) { ov[it] = o4[j]; tv[it] = t4[j]; }
        else {
            ov[it] = make_float4(PAD_O, PAD_O, PAD_O, PAD_O);
            tv[it] = make_float4(0.f, 0.f, 0.f, 0.f);
        }
    }
    __builtin_amdgcn_sched_barrier(0);   // keep ALL loads above any compute

    // ---- Pass 1: neg-set stats + positive-side stats, masked em/tp ----
    float em[16], tp[16];
    float st[5] = {0.f, 0.f, 0.f, 0.f, 0.f};   // Sneg, Tneg, Aneg, Apos, Npos
#pragma unroll
    for (int it = 0; it < 4; ++it) {
        const float oq[4] = {ov[it].x, ov[it].y, ov[it].z, ov[it].w};
        const float tq[4] = {tv[it].x, tv[it].y, tv[it].z, tv[it].w};
#pragma unroll
        for (int q = 0; q < 4; ++q) {
            const float ok = oq[q], tk = tq[q];
            const float e   = __expf(ok);
            const bool neg  = (tk <= 0.5f);
            const float sn  = neg ? e  : 0.0f;   // e on negatives
            const float tn  = neg ? tk : 0.0f;   // t on negatives
            const float tpk = tk - tn;           // t on positives (0 on neg/pad)
            st[0] += sn;
            st[1] += tn;
            st[2]  = fmaf(tn,  ok, st[2]);
            st[3]  = fmaf(tpk, ok, st[3]);
            st[4] += neg ? 0.0f : 1.0f;
            em[4*it+q] = e - sn;                 // e on positives, 0 on neg/pad
            tp[4*it+q] = tpk;
        }
    }
    wave_sum5(st);
    const float S = st[0], T = st[1], A = st[2], Ap = st[3], P = st[4];

    // ---- Pass 2: only em/tp needed; lse for negatives is computed-but-masked ----
    float lsum = 0.f, ltw = 0.f;
#pragma unroll
    for (int k = 0; k < 16; ++k) {
        const float lse = __logf(S + em[k]);     // = log(S) on non-positives (discarded)
        lsum += (tp[k] > 0.5f) ? lse : 0.0f;     // tp>0.5 iff positive
        ltw   = fmaf(tp[k], lse, ltw);
    }
    const float ll = wave_sum(fmaf(T, lsum, ltw));

    float row_loss;
    if (P > 0.5f) row_loss = (ll - fmaf(P, A, Ap)) / P;     // (T*Lsum+Ltw-P*A-Apos)/P
    else          row_loss = fmaf(T, __logf(S), -A);        // rare no-positive fallback

    __shared__ float ls[WPB];
    if (lane == 0) ls[wave] = row_loss;
    __syncthreads();
    if (threadIdx.x == 0)
        partial[blockIdx.x] = (ls[0] + ls[1]) + (ls[2] + ls[3]);
}

__global__ __launch_bounds__(256) void mvce_reduce(
    const float* __restrict__ partial, int n4, float inv_b, float* __restrict__ out)
{
    const float4* p4 = reinterpret_cast<const float4*>(partial);
    float s = 0.f;
#pragma unroll 4
    for (int i = threadIdx.x; i < n4; i += 256) {
        const float4 v = p4[i];
        s += (v.x + v.y) + (v.z + v.w);
    }
    s = wave_sum(s);
    __shared__ float ls[4];
    const int lane = threadIdx.x & 63;
    const int wave = threadIdx.x >> 6;
    if (lane == 0) ls[wave] = s;
    __syncthreads();
    if (threadIdx.x == 0) out[0] = ((ls[0] + ls[1]) + (ls[2] + ls[3])) * inv_b;
}

extern "C" void kernel_launch(void* const* d_in, const int* in_sizes, int n_in,
                              void* d_out, int out_size, void* d_ws, size_t ws_size,
                              hipStream_t stream) {
    const float* outp = (const float*)d_in[0];
    const float* tgtp = (const float*)d_in[1];
    const int Bn = in_sizes[0] / C_DIM;        // 65536
    const int nblocks = Bn / WPB;              // 16384 partials -> 64 KB of d_ws
    float* partial = (float*)d_ws;

    mvce_rows<<<nblocks, 256, 0, stream>>>(outp, tgtp, partial);
    mvce_reduce<<<1, 256, 0, stream>>>(partial, nblocks / 4, 1.0f / (float)Bn,
                                       (float*)d_out);
}